// Round 1
// 1334.143 us; speedup vs baseline: 1.5104x; 1.5104x over previous
//
#include <hip/hip_runtime.h>

#define D 128
#define LN_EPS 1e-5f

static constexpr int cN0 = 20000,  cE0 = 100000;
static constexpr int cN1 = 100000, cE1 = 400000;
static constexpr int cN2 = 400000, cE2 = 800000;

typedef _Float16 f16;
typedef _Float16 f16x8 __attribute__((ext_vector_type(8)));
typedef float f32x4 __attribute__((ext_vector_type(4)));
typedef unsigned short u16x8 __attribute__((ext_vector_type(8)));

// ---------------- f16 helpers ----------------
__device__ inline float h2f(unsigned short u) {
    return (float)__builtin_bit_cast(_Float16, u);
}
__device__ inline unsigned short f2h(float f) {
    return __builtin_bit_cast(unsigned short, (_Float16)f);
}
__device__ inline float4 h4_to_f4(ushort4 v) {
    return make_float4(h2f(v.x), h2f(v.y), h2f(v.z), h2f(v.w));
}

// ---------------- CSR / degree build ----------------

__global__ void k_count(const int* __restrict__ src, const int* __restrict__ dst,
                        int* cnt_out, int* cnt_in, int E) {
    int e = blockIdx.x * blockDim.x + threadIdx.x;
    if (e < E) {
        atomicAdd(&cnt_out[src[e]], 1);
        atomicAdd(&cnt_in[dst[e]], 1);
    }
}

__global__ void k_bsum(const int* __restrict__ cnt, int* bsum, int n) {
    __shared__ int sd[256];
    int t = threadIdx.x;
    int base = blockIdx.x * 1024 + t * 4;
    int s = 0;
#pragma unroll
    for (int i = 0; i < 4; ++i) { int idx = base + i; if (idx < n) s += cnt[idx]; }
    sd[t] = s; __syncthreads();
    for (int off = 128; off > 0; off >>= 1) {
        if (t < off) sd[t] += sd[t + off];
        __syncthreads();
    }
    if (t == 0) bsum[blockIdx.x] = sd[0];
}

__global__ void k_scan_write(const int* __restrict__ cnt, const int* __restrict__ bsum,
                             int* __restrict__ ptr, int n, int E) {
    __shared__ int sd[256];
    __shared__ int so[256];
    int t = threadIdx.x, blk = blockIdx.x;
    int off = 0;
    for (int i = t; i < blk; i += 256) off += bsum[i];
    so[t] = off; __syncthreads();
    for (int o = 128; o > 0; o >>= 1) { if (t < o) so[t] += so[t + o]; __syncthreads(); }
    int boff = so[0];
    int base = blk * 1024 + t * 4;
    int vals[4]; int s = 0;
#pragma unroll
    for (int i = 0; i < 4; ++i) { int idx = base + i; vals[i] = (idx < n) ? cnt[idx] : 0; s += vals[i]; }
    sd[t] = s; __syncthreads();
    for (int o = 1; o < 256; o <<= 1) {
        int x = (t >= o) ? sd[t - o] : 0;
        __syncthreads();
        sd[t] += x;
        __syncthreads();
    }
    int run = boff + sd[t] - s;
#pragma unroll
    for (int i = 0; i < 4; ++i) {
        int idx = base + i;
        if (idx < n) ptr[idx] = run;
        run += vals[i];
    }
    if (blk == 0 && t == 0) ptr[n] = E;
}

__global__ void k_rin_cursor(const int* __restrict__ cnt_out, const int* __restrict__ cnt_in,
                             const int* __restrict__ ptr, float* __restrict__ rout,
                             float* __restrict__ rin, int* __restrict__ cursor, int n) {
    int i = blockIdx.x * blockDim.x + threadIdx.x;
    if (i < n) {
        rout[i] = rsqrtf((float)(cnt_out[i] + 1));  // +1 self-loop
        rin[i]  = rsqrtf((float)(cnt_in[i] + 1));
        cursor[i] = ptr[i];
    }
}

__global__ void k_fill(const int* __restrict__ src, const int* __restrict__ dst,
                       int* cursor, int* __restrict__ eid, int* __restrict__ srcs, int E) {
    int e = blockIdx.x * blockDim.x + threadIdx.x;
    if (e < E) {
        int p = atomicAdd(&cursor[dst[e]], 1);
        eid[p] = e;
        srcs[p] = src[e];
    }
}

// ---------------- fusion input: td = segment_sum(child_h, dst) via CSR ----------------
__global__ void k_segsum_rows(float* __restrict__ X, const int* __restrict__ ptr,
                              const int* __restrict__ eid, const float* __restrict__ table,
                              int n) {
    int wid = (blockIdx.x * blockDim.x + threadIdx.x) >> 6;
    int lane = threadIdx.x & 63;
    if (wid >= n) return;
    int j = lane * 2;
    float2 acc = make_float2(0.f, 0.f);
    int p0 = ptr[wid], p1 = ptr[wid + 1];
    for (int p = p0; p < p1; ++p) {
        int e = eid[p];
        const float2 x = *(const float2*)(table + (size_t)e * D + j);
        acc.x += x.x; acc.y += x.y;
    }
    *(float2*)(X + (size_t)wid * D + j) = acc;
}

// ---------------- weight prep: transpose + f16 convert ----------------
// convW/fusW: 3x[128][128] -> Wt[n][k]; catW: 3x[256][128] -> Wt[n=128][k=256]
__global__ void k_prep_w(const float* __restrict__ convW, const float* __restrict__ fusW,
                         const float* __restrict__ catW,
                         unsigned short* __restrict__ cWt, unsigned short* __restrict__ fWt,
                         unsigned short* __restrict__ kWt) {
    int t = blockIdx.x * 256 + threadIdx.x;
    if (t < 98304) {
        int mi = t / 16384, r = t % 16384;     // matrix 0..5 (3 conv, 3 fus)
        const float* W = (mi < 3) ? (convW + mi * 16384) : (fusW + (mi - 3) * 16384);
        unsigned short* T = (mi < 3) ? (cWt + mi * 16384) : (fWt + (mi - 3) * 16384);
        int n = r >> 7, k = r & 127;           // out [n][k], K=128
        T[r] = f2h(W[k * 128 + n]);
    } else if (t < 196608) {
        int t2 = t - 98304;
        int mi = t2 / 32768, r = t2 % 32768;
        int n = r >> 8, k = r & 255;           // out [n][k], K=256
        kWt[mi * 32768 + r] = f2h(catW[mi * 32768 + k * 128 + n]);
    }
}

// ---------------- gconv GEMM (MFMA f16): HN = rout ⊙ (A[ridx] @ W) ----------------
// Block: 128 rows x 128 cols, 4 waves x 32 rows. a-op = Wt frag (LDS, swizzled),
// b-op = A row frag (direct global->reg, fp32->f16). D[n][m]: lane m=l&15, regs = 4 consec n.
template<bool GATHER>
__global__ __launch_bounds__(256) void k_gconv_mfma(
        const float* __restrict__ A, const int* __restrict__ ridx,
        const float* __restrict__ rs, const unsigned short* __restrict__ Wt,
        unsigned short* __restrict__ C, int M) {
    __shared__ __align__(16) unsigned short Ws[128 * 128];   // 32 KiB, XOR-swizzled
    int tid = threadIdx.x;
#pragma unroll
    for (int i = 0; i < 8; ++i) {
        int lb = (tid + i * 256) << 4;          // linear byte, row = 256B
        int n = lb >> 8;
        int sw = lb ^ ((n & 7) << 4);
        *(u16x8*)((char*)Ws + sw) = *(const u16x8*)((const char*)Wt + lb);
    }
    __syncthreads();
    int w = tid >> 6, l = tid & 63;
    int g = l >> 4, ln = l & 15;
    int row0 = blockIdx.x * 128 + w * 32;
    int m0 = row0 + ln, m1 = m0 + 16;
    bool v0 = m0 < M, v1 = m1 < M;
    int sr0 = m0, sr1 = m1;
    if (GATHER) {
        sr0 = v0 ? ridx[m0] : 0;
        sr1 = v1 ? ridx[m1] : 0;
    }
    const float* a0p = A + (size_t)sr0 * 128;
    const float* a1p = A + (size_t)sr1 * 128;
    f32x4 acc[2][8] = {};
#pragma unroll
    for (int k0 = 0; k0 < 128; k0 += 32) {
        int kk = k0 + g * 8;
        f16x8 b0 = {}, b1 = {};
        if (v0) {
            float4 x = *(const float4*)(a0p + kk);
            float4 y = *(const float4*)(a0p + kk + 4);
            b0[0] = (f16)x.x; b0[1] = (f16)x.y; b0[2] = (f16)x.z; b0[3] = (f16)x.w;
            b0[4] = (f16)y.x; b0[5] = (f16)y.y; b0[6] = (f16)y.z; b0[7] = (f16)y.w;
        }
        if (v1) {
            float4 x = *(const float4*)(a1p + kk);
            float4 y = *(const float4*)(a1p + kk + 4);
            b1[0] = (f16)x.x; b1[1] = (f16)x.y; b1[2] = (f16)x.z; b1[3] = (f16)x.w;
            b1[4] = (f16)y.x; b1[5] = (f16)y.y; b1[6] = (f16)y.z; b1[7] = (f16)y.w;
        }
#pragma unroll
        for (int nf = 0; nf < 8; ++nf) {
            int n = nf * 16 + ln;
            int sw = (n * 256 + kk * 2) ^ ((n & 7) << 4);
            f16x8 a = *(const f16x8*)((const char*)Ws + sw);
            acc[0][nf] = __builtin_amdgcn_mfma_f32_16x16x32_f16(a, b0, acc[0][nf], 0, 0, 0);
            acc[1][nf] = __builtin_amdgcn_mfma_f32_16x16x32_f16(a, b1, acc[1][nf], 0, 0, 0);
        }
    }
    float s0 = v0 ? rs[m0] : 0.f;
    float s1 = v1 ? rs[m1] : 0.f;
#pragma unroll
    for (int mf = 0; mf < 2; ++mf) {
        int m = mf ? m1 : m0;
        if (m >= M) continue;
        float s = mf ? s1 : s0;
        unsigned short* cp = C + (size_t)m * 128 + g * 4;
#pragma unroll
        for (int nf = 0; nf < 8; ++nf) {
            f32x4 v = acc[mf][nf];
            ushort4 o;
            o.x = f2h(v[0] * s); o.y = f2h(v[1] * s);
            o.z = f2h(v[2] * s); o.w = f2h(v[3] * s);
            *(ushort4*)(cp + nf * 16) = o;
        }
    }
}

// ---------------- one-pass multi-term aggregation + relu-concat (f16 in/out) ----------------
template<int NT>
__global__ void k_agg_multi(const unsigned short* __restrict__ H0,
                            const unsigned short* __restrict__ H1,
                            const unsigned short* __restrict__ H2,
                            const int* __restrict__ ptr, const int* __restrict__ srcs,
                            const float* __restrict__ rin,
                            const float* __restrict__ b0, const float* __restrict__ b1,
                            const float* __restrict__ b2,
                            const float* __restrict__ c0, const float* __restrict__ c1,
                            const float* __restrict__ c2,
                            unsigned short* __restrict__ RES, int n) {
    int node = (blockIdx.x * blockDim.x + threadIdx.x) >> 5;
    int lane = threadIdx.x & 31;
    if (node >= n) return;
    int j = lane * 4;

    float4 a0 = make_float4(0.f, 0.f, 0.f, 0.f), a1 = a0, a2 = a0;
    a0 = h4_to_f4(*(const ushort4*)(H0 + (size_t)node * D + j));
    if (NT > 1) a1 = h4_to_f4(*(const ushort4*)(H1 + (size_t)node * D + j));
    if (NT > 2) a2 = h4_to_f4(*(const ushort4*)(H2 + (size_t)node * D + j));

    int p0 = ptr[node], p1 = ptr[node + 1];
    for (int p = p0; p < p1; ++p) {
        int s = srcs[p];
        float4 x0 = h4_to_f4(*(const ushort4*)(H0 + (size_t)s * D + j));
        a0.x += x0.x; a0.y += x0.y; a0.z += x0.z; a0.w += x0.w;
        if (NT > 1) {
            float4 x1 = h4_to_f4(*(const ushort4*)(H1 + (size_t)s * D + j));
            a1.x += x1.x; a1.y += x1.y; a1.z += x1.z; a1.w += x1.w;
        }
        if (NT > 2) {
            float4 x2 = h4_to_f4(*(const ushort4*)(H2 + (size_t)s * D + j));
            a2.x += x2.x; a2.y += x2.y; a2.z += x2.z; a2.w += x2.w;
        }
    }

    float ri = rin[node];
    float4 bb0 = *(const float4*)(b0 + j);
    float4 cc0 = *(const float4*)(c0 + j);
    float4 v, rsum, ssum;
    v.x = (a0.x * ri + bb0.x) * cc0.x;
    v.y = (a0.y * ri + bb0.y) * cc0.y;
    v.z = (a0.z * ri + bb0.z) * cc0.z;
    v.w = (a0.w * ri + bb0.w) * cc0.w;
    rsum = make_float4(fmaxf(v.x, 0.f), fmaxf(v.y, 0.f), fmaxf(v.z, 0.f), fmaxf(v.w, 0.f));
    ssum = v;
    if (NT > 1) {
        float4 bb = *(const float4*)(b1 + j);
        float4 cc = *(const float4*)(c1 + j);
        v.x = (a1.x * ri + bb.x) * cc.x;
        v.y = (a1.y * ri + bb.y) * cc.y;
        v.z = (a1.z * ri + bb.z) * cc.z;
        v.w = (a1.w * ri + bb.w) * cc.w;
        rsum.x += fmaxf(v.x, 0.f); rsum.y += fmaxf(v.y, 0.f);
        rsum.z += fmaxf(v.z, 0.f); rsum.w += fmaxf(v.w, 0.f);
        ssum.x += v.x; ssum.y += v.y; ssum.z += v.z; ssum.w += v.w;
    }
    if (NT > 2) {
        float4 bb = *(const float4*)(b2 + j);
        float4 cc = *(const float4*)(c2 + j);
        v.x = (a2.x * ri + bb.x) * cc.x;
        v.y = (a2.y * ri + bb.y) * cc.y;
        v.z = (a2.z * ri + bb.z) * cc.z;
        v.w = (a2.w * ri + bb.w) * cc.w;
        rsum.x += fmaxf(v.x, 0.f); rsum.y += fmaxf(v.y, 0.f);
        rsum.z += fmaxf(v.z, 0.f); rsum.w += fmaxf(v.w, 0.f);
        ssum.x += v.x; ssum.y += v.y; ssum.z += v.z; ssum.w += v.w;
    }
    unsigned short* r = RES + (size_t)node * (2 * D) + j;
    ushort4 o1, o2;
    o1.x = f2h(rsum.x); o1.y = f2h(rsum.y); o1.z = f2h(rsum.z); o1.w = f2h(rsum.w);
    o2.x = f2h(ssum.x); o2.y = f2h(ssum.y); o2.z = f2h(ssum.z); o2.w = f2h(ssum.w);
    *(ushort4*)r = o1;
    *(ushort4*)(r + D) = o2;
}

// ---------------- cat projection + LayerNorm (MFMA f16) ----------------
__global__ __launch_bounds__(256) void k_cat_ln_mfma(
        const unsigned short* __restrict__ RESh, const unsigned short* __restrict__ Wt,
        const float* __restrict__ bias, const float* __restrict__ gam,
        const float* __restrict__ bet, float* __restrict__ out, int M) {
    __shared__ __align__(16) unsigned short Ws[128 * 256];   // 64 KiB, XOR-swizzled
    int tid = threadIdx.x;
#pragma unroll
    for (int i = 0; i < 16; ++i) {
        int lb = (tid + i * 256) << 4;          // linear byte, row = 512B
        int n = lb >> 9;
        int sw = lb ^ ((n & 7) << 4);
        *(u16x8*)((char*)Ws + sw) = *(const u16x8*)((const char*)Wt + lb);
    }
    __syncthreads();
    int w = tid >> 6, l = tid & 63;
    int g = l >> 4, ln = l & 15;
    int row0 = blockIdx.x * 128 + w * 32;
    int m0 = row0 + ln, m1 = m0 + 16;
    bool v0 = m0 < M, v1 = m1 < M;
    const unsigned short* r0p = RESh + (size_t)m0 * 256;
    const unsigned short* r1p = RESh + (size_t)m1 * 256;
    f32x4 acc[2][8] = {};
#pragma unroll
    for (int k0 = 0; k0 < 256; k0 += 32) {
        int kk = k0 + g * 8;
        f16x8 b0 = {}, b1 = {};
        if (v0) b0 = *(const f16x8*)(r0p + kk);
        if (v1) b1 = *(const f16x8*)(r1p + kk);
#pragma unroll
        for (int nf = 0; nf < 8; ++nf) {
            int n = nf * 16 + ln;
            int sw = (n * 512 + kk * 2) ^ ((n & 7) << 4);
            f16x8 a = *(const f16x8*)((const char*)Ws + sw);
            acc[0][nf] = __builtin_amdgcn_mfma_f32_16x16x32_f16(a, b0, acc[0][nf], 0, 0, 0);
            acc[1][nf] = __builtin_amdgcn_mfma_f32_16x16x32_f16(a, b1, acc[1][nf], 0, 0, 0);
        }
    }
#pragma unroll
    for (int mf = 0; mf < 2; ++mf) {
        float x[8][4];
        float s = 0.f, ss = 0.f;
#pragma unroll
        for (int nf = 0; nf < 8; ++nf) {
            float4 b = *(const float4*)(bias + nf * 16 + g * 4);
            f32x4 v = acc[mf][nf];
            x[nf][0] = v[0] + b.x; x[nf][1] = v[1] + b.y;
            x[nf][2] = v[2] + b.z; x[nf][3] = v[3] + b.w;
            s += x[nf][0] + x[nf][1] + x[nf][2] + x[nf][3];
            ss += x[nf][0] * x[nf][0] + x[nf][1] * x[nf][1]
                + x[nf][2] * x[nf][2] + x[nf][3] * x[nf][3];
        }
        s  += __shfl_xor(s, 16, 64);  s  += __shfl_xor(s, 32, 64);
        ss += __shfl_xor(ss, 16, 64); ss += __shfl_xor(ss, 32, 64);
        float mu = s * (1.0f / 128.0f);
        float var = ss * (1.0f / 128.0f) - mu * mu;
        float inv = rsqrtf(var + LN_EPS);
        int m = mf ? m1 : m0;
        if (m < M) {
            float* op = out + (size_t)m * 128 + g * 4;
#pragma unroll
            for (int nf = 0; nf < 8; ++nf) {
                float4 gv = *(const float4*)(gam + nf * 16 + g * 4);
                float4 ev = *(const float4*)(bet + nf * 16 + g * 4);
                float4 o;
                o.x = (x[nf][0] - mu) * inv * gv.x + ev.x;
                o.y = (x[nf][1] - mu) * inv * gv.y + ev.y;
                o.z = (x[nf][2] - mu) * inv * gv.z + ev.z;
                o.w = (x[nf][3] - mu) * inv * gv.w + ev.w;
                *(float4*)(op + nf * 16) = o;
            }
        }
    }
}

__global__ void k_ws_too_small(float* out) {
    if (threadIdx.x == 0 && blockIdx.x == 0) out[0] = 12345678.f;
}

// ---------------- orchestration ----------------

struct Lvl {
    int n, E;
    const int *src, *dst;
    int *cnt_out, *cnt_in, *ptr, *cursor, *eid, *srcs;
    float *rout, *rin;
};

static inline char* bump(char*& p, size_t bytes, void** out) {
    *out = (void*)p;
    p += (bytes + 255) & ~(size_t)255;
    return p;
}

extern "C" void kernel_launch(void* const* d_in, const int* in_sizes, int n_in,
                              void* d_out, int out_size, void* d_ws, size_t ws_size,
                              hipStream_t stream) {
    const float* h0 = (const float*)d_in[0];
    const float* h1 = (const float*)d_in[1];
    const float* h2 = (const float*)d_in[2];
    const int* src0 = (const int*)d_in[3];
    const int* dst0 = (const int*)d_in[4];
    const int* src1 = (const int*)d_in[5];
    const int* dst1 = (const int*)d_in[6];
    const int* src2 = (const int*)d_in[7];
    const int* dst2 = (const int*)d_in[8];
    const float* convW = (const float*)d_in[9];
    const float* convb = (const float*)d_in[10];
    const float* fusW  = (const float*)d_in[11];
    const float* fusb  = (const float*)d_in[12];
    const float* catW  = (const float*)d_in[13];
    const float* catb  = (const float*)d_in[14];
    const float* convw = (const float*)d_in[15];
    const float* tdw   = (const float*)d_in[16];
    const float* buw   = (const float*)d_in[17];
    const float* lng   = (const float*)d_in[18];
    const float* lnb   = (const float*)d_in[19];
    float* out = (float*)d_out;

    // workspace carve-out
    char* p = (char*)d_ws;
    void *vX, *vHNa, *vHNb, *vHNc, *vRES, *vbsum, *vcWt, *vfWt, *vkWt;
    bump(p, (size_t)cN1 * D * 4, &vX);            // fp32 td staging (levels 0,1)
    bump(p, (size_t)cN2 * D * 2, &vHNa);          // f16 HN term a
    bump(p, (size_t)cN2 * D * 2, &vHNb);          // f16 HN term b
    bump(p, (size_t)cN1 * D * 2, &vHNc);          // f16 HN term c (level 1 only)
    bump(p, (size_t)cN2 * 2 * D * 2, &vRES);      // f16 relu-concat result
    bump(p, 512 * 4, &vbsum);
    bump(p, (size_t)3 * 128 * 128 * 2, &vcWt);    // f16 convW^T
    bump(p, (size_t)3 * 128 * 128 * 2, &vfWt);    // f16 fusW^T
    bump(p, (size_t)3 * 128 * 256 * 2, &vkWt);    // f16 catW^T
    float* X = (float*)vX;
    unsigned short* HNa = (unsigned short*)vHNa;
    unsigned short* HNb = (unsigned short*)vHNb;
    unsigned short* HNc = (unsigned short*)vHNc;
    unsigned short* RESh = (unsigned short*)vRES;
    int* bsum = (int*)vbsum;
    unsigned short* cWt = (unsigned short*)vcWt;
    unsigned short* fWt = (unsigned short*)vfWt;
    unsigned short* kWt = (unsigned short*)vkWt;

    Lvl lv[3];
    lv[0] = {cN0, cE0, src0, dst0};
    lv[1] = {cN1, cE1, src1, dst1};
    lv[2] = {cN2, cE2, src2, dst2};
    for (int L = 0; L < 3; ++L) {
        Lvl& v = lv[L];
        void* t;
        bump(p, (size_t)v.n * 4, &t);       v.cnt_out = (int*)t;
        bump(p, (size_t)v.n * 4, &t);       v.cnt_in  = (int*)t;
        bump(p, (size_t)(v.n + 1) * 4, &t); v.ptr     = (int*)t;
        bump(p, (size_t)v.n * 4, &t);       v.cursor  = (int*)t;
        bump(p, (size_t)v.E * 4, &t);       v.eid     = (int*)t;
        bump(p, (size_t)v.E * 4, &t);       v.srcs    = (int*)t;
        bump(p, (size_t)v.n * 4, &t);       v.rout    = (float*)t;
        bump(p, (size_t)v.n * 4, &t);       v.rin     = (float*)t;
    }
    size_t need = (size_t)(p - (char*)d_ws);
    if (need > ws_size) {
        hipLaunchKernelGGL(k_ws_too_small, dim3(1), dim3(64), 0, stream, out);
        return;
    }

    // transpose + f16-convert all weights (once per launch)
    k_prep_w<<<768, 256, 0, stream>>>(convW, fusW, catW, cWt, fWt, kWt);

    for (int L = 0; L < 3; ++L) {
        Lvl& v = lv[L];
        hipMemsetAsync(v.cnt_out, 0, (size_t)v.n * 4, stream);
        hipMemsetAsync(v.cnt_in, 0, (size_t)v.n * 4, stream);
        k_count<<<(v.E + 255) / 256, 256, 0, stream>>>(v.src, v.dst, v.cnt_out, v.cnt_in, v.E);
        int nb = (v.n + 1023) / 1024;
        k_bsum<<<nb, 256, 0, stream>>>(v.cnt_in, bsum, v.n);
        k_scan_write<<<nb, 256, 0, stream>>>(v.cnt_in, bsum, v.ptr, v.n, v.E);
        k_rin_cursor<<<(v.n + 255) / 256, 256, 0, stream>>>(v.cnt_out, v.cnt_in, v.ptr,
                                                            v.rout, v.rin, v.cursor, v.n);
        k_fill<<<(v.E + 255) / 256, 256, 0, stream>>>(v.src, v.dst, v.cursor, v.eid, v.srcs, v.E);
    }

    auto gemm = [&](int L, const float* A, const int* ridx, const unsigned short* Wt,
                    unsigned short* HN) {
        Lvl& v = lv[L];
        int nb = (v.n + 127) / 128;
        if (ridx)
            k_gconv_mfma<true><<<nb, 256, 0, stream>>>(A, ridx, v.rout, Wt, HN, v.n);
        else
            k_gconv_mfma<false><<<nb, 256, 0, stream>>>(A, nullptr, v.rout, Wt, HN, v.n);
    };

    // ---- level 0 (params idx 0): conv(h0) + td0 = segsum(h1 over dst0) ----
    {
        Lvl& v = lv[0];
        gemm(0, h0, nullptr, cWt, HNa);
        k_segsum_rows<<<(cN0 + 3) / 4, 256, 0, stream>>>(X, v.ptr, v.eid, h1, cN0);
        gemm(0, X, nullptr, fWt, HNb);
        k_agg_multi<2><<<(cN0 * 32 + 255) / 256, 256, 0, stream>>>(
            HNa, HNb, HNa, v.ptr, v.srcs, v.rin,
            convb + 0, fusb + 0, convb + 0,
            convw + 0, tdw + 0, convw + 0, RESh, cN0);
        k_cat_ln_mfma<<<(cN0 + 127) / 128, 256, 0, stream>>>(RESh, kWt, catb + 0,
                                                             lng + 0, lnb + 0, out, cN0);
    }

    // ---- level 1 (params idx 2): conv(h1) + bu1 = h0[dst0] + td1 = segsum(h2 over dst1) ----
    {
        Lvl& v = lv[1];
        const int o1 = 2 * D;
        gemm(1, h1, nullptr, cWt + 2 * 16384, HNa);
        gemm(1, h0, dst0, fWt + 2 * 16384, HNb);    // bu1 gathered in-GEMM
        k_segsum_rows<<<(cN1 + 3) / 4, 256, 0, stream>>>(X, v.ptr, v.eid, h2, cN1);
        gemm(1, X, nullptr, fWt + 2 * 16384, HNc);
        k_agg_multi<3><<<(cN1 * 32 + 255) / 256, 256, 0, stream>>>(
            HNa, HNb, HNc, v.ptr, v.srcs, v.rin,
            convb + o1, fusb + o1, fusb + o1,
            convw + o1, buw + o1, tdw + o1, RESh, cN1);
        k_cat_ln_mfma<<<(cN1 + 127) / 128, 256, 0, stream>>>(RESh, kWt + 2 * 32768, catb + o1,
                                                             lng + o1, lnb + o1,
                                                             out + (size_t)cN0 * D, cN1);
    }

    // ---- level 2 (params idx 1): conv(h2) + bu2 = h1[dst1] ----
    {
        Lvl& v = lv[2];
        const int o1 = 1 * D;
        gemm(2, h2, nullptr, cWt + 1 * 16384, HNa);
        gemm(2, h1, dst1, fWt + 1 * 16384, HNb);    // bu2 gathered in-GEMM
        k_agg_multi<2><<<(cN2 * 32 + 255) / 256, 256, 0, stream>>>(
            HNa, HNb, HNa, v.ptr, v.srcs, v.rin,
            convb + o1, fusb + o1, convb + o1,
            convw + o1, buw + o1, convw + o1, RESh, cN2);
        k_cat_ln_mfma<<<(cN2 + 127) / 128, 256, 0, stream>>>(RESh, kWt + 1 * 32768, catb + o1,
                                                             lng + o1, lnb + o1,
                                                             out + (size_t)(cN0 + cN1) * D, cN2);
    }
}